// Round 9
// baseline (191.110 us; speedup 1.0000x reference)
//
#include <hip/hip_runtime.h>
#include <stdint.h>

typedef unsigned short ushort_t;
typedef __bf16 bf16x8 __attribute__((ext_vector_type(8)));
typedef float f32x4 __attribute__((ext_vector_type(4)));

#define DIM 1024
#define HEADS 16
#define HD 64
#define BATCH 2
#define SEQ 2048
#define MTOT (BATCH*SEQ)   // 4096

// exp2 scale: log2(e)/sqrt(1024)
#define C2F 0.045084220027780106f

__device__ __forceinline__ ushort_t f2bf(float f) {
    uint32_t u = __float_as_uint(f);
    uint32_t r = (u + 0x7FFFu + ((u >> 16) & 1u)) >> 16;
    return (ushort_t)r;
}

// truncating bf16 pack via one v_perm_b32 (bias cancels in softmax ratio)
__device__ __forceinline__ uint32_t permpack(float lo, float hi) {
    return __builtin_amdgcn_perm(__float_as_uint(hi), __float_as_uint(lo), 0x07060302u);
}

__device__ __forceinline__ f32x4 mfma16(bf16x8 a, bf16x8 b, f32x4 c) {
    return __builtin_amdgcn_mfma_f32_16x16x32_bf16(a, b, c, 0, 0, 0);
}

// async global->LDS, 16B per lane; LDS dest = wave-uniform base + lane*16
__device__ __forceinline__ void glds16(const ushort_t* g, ushort_t* l) {
    __builtin_amdgcn_global_load_lds(
        (const __attribute__((address_space(1))) unsigned int*)g,
        (__attribute__((address_space(3))) unsigned int*)l, 16, 0, 0);
}

// ---------------- fused prep: weight transpose+permute (z<4) / x fp32->bf16 (z==4) ----------------
__global__ void k_prep(const float* __restrict__ x,
                       const float* __restrict__ w0, const float* __restrict__ w1,
                       const float* __restrict__ w2, const float* __restrict__ w3,
                       ushort_t* __restrict__ wt, ushort_t* __restrict__ xb) {
    const int z = blockIdx.z;
    int tx = threadIdx.x, ty = threadIdx.y; // (32, 8)
    if (z == 4) {
        int bid = blockIdx.y * 32 + blockIdx.x;
        int t = ty * 32 + tx;
#pragma unroll
        for (int u = 0; u < 4; u++) {
            int i = bid * 1024 + u * 256 + t;
            const float4 v = ((const float4*)x)[i];
            ushort4 o;
            o.x = f2bf(v.x); o.y = f2bf(v.y); o.z = f2bf(v.z); o.w = f2bf(v.w);
            ((ushort4*)xb)[i] = o;
        }
        return;
    }
    __shared__ float t[32][33];
    const float* w = (z == 0) ? w0 : (z == 1) ? w1 : (z == 2) ? w2 : w3;
    ushort_t* o = wt + (size_t)z * DIM * DIM;
    int n0 = blockIdx.x * 32;
    int k0 = blockIdx.y * 32;
    if (z < 3) {
#pragma unroll
        for (int i = 0; i < 4; i++)
            t[ty + i * 8][tx] = w[(size_t)(k0 + ty + i * 8) * DIM + n0 + tx];
        __syncthreads();
#pragma unroll
        for (int i = 0; i < 4; i++) {
            int n = n0 + ty + i * 8;
            int np = (n & 15) * 64 + (n >> 4);
            o[(size_t)np * DIM + k0 + tx] = f2bf(t[tx][ty + i * 8]);
        }
    } else {
#pragma unroll
        for (int i = 0; i < 4; i++) {
            int kp = k0 + ty + i * 8;
            int k = (kp & 63) * 16 + (kp >> 6);
            t[ty + i * 8][tx] = w[(size_t)k * DIM + n0 + tx];
        }
        __syncthreads();
#pragma unroll
        for (int i = 0; i < 4; i++)
            o[(size_t)(n0 + ty + i * 8) * DIM + k0 + tx] = f2bf(t[tx][ty + i * 8]);
    }
}

// ---------------- fused QKV projection GEMM (BK=64, operand-swapped) ----------------
__global__ __launch_bounds__(256) void k_qkv(const ushort_t* __restrict__ xb,
                                             const ushort_t* __restrict__ wt,
                                             ushort_t* __restrict__ qp,
                                             ushort_t* __restrict__ kp,
                                             ushort_t* __restrict__ vp) {
    __shared__ __align__(16) ushort_t lA[128 * 64]; // 16 KB
    __shared__ __align__(16) ushort_t lB[128 * 64];
    const int z = blockIdx.z;
    const ushort_t* w = wt + (size_t)z * DIM * DIM;
    ushort_t* dst = (z == 0) ? qp : (z == 1) ? kp : vp;
    const float sc = (z == 0) ? C2F : 1.0f;
    const int tid = threadIdx.x;
    const int wave = tid >> 6;
    const int lane = tid & 63;
    const int l16 = lane & 15;
    const int quad = lane >> 4;
    const int m0 = blockIdx.x * 128;
    const int n0 = blockIdx.y * 128;
    const int mw = (wave & 1) * 64, nw = (wave >> 1) * 64;

    const f32x4 zero4 = {0.f, 0.f, 0.f, 0.f};
    f32x4 acc[4][4];
#pragma unroll
    for (int i = 0; i < 4; i++)
#pragma unroll
        for (int j = 0; j < 4; j++) acc[i][j] = zero4;

    const int swz = l16 & 7;
    for (int k0 = 0; k0 < DIM; k0 += 64) {
        __syncthreads();
#pragma unroll
        for (int j = 0; j < 4; j++) {
            int base = wave * 256 + j * 64;
            int L = base + lane;
            int row = L >> 3, cd = L & 7;
            int cs = cd ^ (row & 7);
            glds16(xb + (size_t)(m0 + row) * DIM + k0 + cs * 8, lA + base * 8);
            glds16(w + (size_t)(n0 + row) * DIM + k0 + cs * 8, lB + base * 8);
        }
        __syncthreads();
#pragma unroll
        for (int kk = 0; kk < 2; kk++) {
            bf16x8 a[4], b[4];
#pragma unroll
            for (int i = 0; i < 4; i++) {
                int rowa = mw + i * 16 + l16;
                int rowb = nw + i * 16 + l16;
                int ch = (kk * 4 + quad) ^ swz;
                a[i] = *(const bf16x8*)(lA + rowa * 64 + ch * 8);
                b[i] = *(const bf16x8*)(lB + rowb * 64 + ch * 8);
            }
#pragma unroll
            for (int ni = 0; ni < 4; ni++)
#pragma unroll
                for (int mi = 0; mi < 4; mi++)
                    acc[ni][mi] = mfma16(b[ni], a[mi], acc[ni][mi]);
        }
    }

#pragma unroll
    for (int ni = 0; ni < 4; ni++)
#pragma unroll
        for (int mi = 0; mi < 4; mi++) {
            int nbase = n0 + nw + ni * 16 + quad * 4;
            int m = m0 + mw + mi * 16 + l16;
            ushort4 o;
            o.x = f2bf(acc[ni][mi][0] * sc);
            o.y = f2bf(acc[ni][mi][1] * sc);
            o.z = f2bf(acc[ni][mi][2] * sc);
            o.w = f2bf(acc[ni][mi][3] * sc);
            *(ushort4*)(dst + (size_t)m * DIM + nbase) = o;
        }
}

// ---------------- V transpose: vt[bh][i][s] = vp[(b*S+s)*D + h*64+i] ----------------
__global__ void k_vt(const ushort_t* __restrict__ vp, ushort_t* __restrict__ vt) {
    __shared__ ushort_t t[32][34];
    const int bh = blockIdx.z, b = bh >> 4, h = bh & 15;
    const int s0 = blockIdx.x * 32;
    const int i0 = blockIdx.y * 32;
    int tx = threadIdx.x, ty = threadIdx.y; // (32,8)
#pragma unroll
    for (int j = 0; j < 4; j++)
        t[ty + j * 8][tx] = vp[(size_t)(b * SEQ + s0 + ty + j * 8) * DIM + h * HD + i0 + tx];
    __syncthreads();
#pragma unroll
    for (int j = 0; j < 4; j++)
        vt[((size_t)bh * HD + i0 + ty + j * 8) * SEQ + s0 + tx] = t[tx][ty + j * 8];
}

// ---------------- flash attention: 128-wide KV staging, 2 compute passes/barrier ----------------
// 256 thr / 4 waves; block handles complementary q-tile pair {bx, 31-bx}
// (17 barrier-iters/block, perfectly balanced). K/V double-buffered 32KB/tile,
// ONE barrier per 128 kseq. Fully-masked 64-halves skipped wave-uniformly.
// Static-max softmax (bounded scores), truncate-packed P, MFMA denominator.
__global__ __launch_bounds__(256) void k_attn(const ushort_t* __restrict__ qp,
                                              const ushort_t* __restrict__ kp,
                                              const ushort_t* __restrict__ vt,
                                              ushort_t* __restrict__ mg) {
    __shared__ __align__(16) ushort_t lK[2][128 * 64]; // 128 kseq x 64 hd (128B rows)
    __shared__ __align__(16) ushort_t lV[2][64 * 128]; // 64 vd x 128 kseq (256B rows)
    __shared__ __align__(16) ushort_t lP[4][16 * 72];  // per-wave P^T staging
    const int tid = threadIdx.x;
    const int w = tid >> 6;
    const int lane = tid & 63;
    const int l16 = lane & 15;
    const int quad = lane >> 4;
    const int bh = blockIdx.y, b = bh >> 4, h = bh & 15;

    const ushort_t* Q = qp + (size_t)b * SEQ * DIM + h * HD;
    const ushort_t* K = kp + (size_t)b * SEQ * DIM + h * HD;
    const ushort_t* V = vt + (size_t)bh * HD * SEQ;

    const int swz = l16 & 7;   // K rows: 8 chunks
    const int swzv = l16;      // V rows: 16 chunks
    ushort_t* pw = lP[w] + l16 * 72;

    union { ushort_t u[8]; bf16x8 v; } one8;
#pragma unroll
    for (int j = 0; j < 8; j++) one8.u[j] = 0x3F80; // bf16 1.0

#pragma unroll 1
    for (int phase = 0; phase < 2; phase++) {
        const int qi = phase ? (31 - (int)blockIdx.x) : (int)blockIdx.x;
        const int qb = qi * 64;
        const int mb = qb + w * 16;
        const int nt = (qb >> 7) + 1; // 128-wide KV tiles covering [0, qb+64)

        bf16x8 qf[2];
#pragma unroll
        for (int hf = 0; hf < 2; hf++)
            qf[hf] = *(const bf16x8*)(Q + (size_t)(mb + l16) * DIM + hf * 32 + quad * 8);

        const f32x4 zero4 = {0.f, 0.f, 0.f, 0.f};
        f32x4 oT[4];
#pragma unroll
        for (int nb = 0; nb < 4; nb++) oT[nb] = zero4;
        f32x4 ls = zero4;

        __syncthreads(); // protect LDS bufs still read in previous phase
        // prologue: stage tile 0 (32KB) into buf 0
#pragma unroll
        for (int j = 0; j < 4; j++) {
            int base = w * 256 + j * 64;
            int L = base + lane;
            int rk = L >> 3, ck = L & 7;
            glds16(K + (size_t)rk * DIM + (ck ^ (rk & 7)) * 8, lK[0] + base * 8);
            int rv = L >> 4, cv = L & 15;
            glds16(V + (size_t)rv * SEQ + (cv ^ (rv & 15)) * 8, lV[0] + base * 8);
        }

        int cur = 0;
        for (int kt = 0; kt < nt; kt++) {
            const int kb = kt * 128;
            __syncthreads(); // drains vmcnt: buf[cur] ready; buf[cur^1] free
            if (kt + 1 < nt) {
                const int kb2 = kb + 128;
#pragma unroll
                for (int j = 0; j < 4; j++) {
                    int base = w * 256 + j * 64;
                    int L = base + lane;
                    int rk = L >> 3, ck = L & 7;
                    glds16(K + (size_t)(kb2 + rk) * DIM + (ck ^ (rk & 7)) * 8,
                           lK[cur ^ 1] + base * 8);
                    int rv = L >> 4, cv = L & 15;
                    glds16(V + (size_t)rv * SEQ + kb2 + (cv ^ (rv & 15)) * 8,
                           lV[cur ^ 1] + base * 8);
                }
            }

#pragma unroll
            for (int half = 0; half < 2; half++) {
                const int kh = kb + half * 64;
                if (kh > mb + 15) continue; // fully-masked half (wave-uniform)

                // K A-frags [m=kseq][k=hd]; V^T A-frags [m=vdim][k=kseq]
                bf16x8 kf[4][2], vf[4][2];
#pragma unroll
                for (int c = 0; c < 4; c++)
#pragma unroll
                    for (int hf = 0; hf < 2; hf++) {
                        int row = half * 64 + c * 16 + l16;
                        int ch = (hf * 4 + quad) ^ swz;
                        kf[c][hf] = *(const bf16x8*)(lK[cur] + row * 64 + ch * 8);
                    }
#pragma unroll
                for (int nb = 0; nb < 4; nb++)
#pragma unroll
                    for (int pr = 0; pr < 2; pr++) {
                        int row = nb * 16 + l16;
                        int ch = (half * 8 + pr * 4 + quad) ^ swzv;
                        vf[nb][pr] = *(const bf16x8*)(lV[cur] + row * 128 + ch * 8);
                    }

                // S^T: D row = kseq (quad*4+r), col = q (l16)
                f32x4 s4[4];
#pragma unroll
                for (int c = 0; c < 4; c++) {
                    f32x4 t = zero4;
                    t = mfma16(kf[c][0], qf[0], t);
                    t = mfma16(kf[c][1], qf[1], t);
                    s4[c] = t;
                }

                // mask needed iff any key in [kh, kh+63] exceeds the wave's
                // minimum q-row mb  (R8 bug: kh+48>mb missed the mb==kh+48 wave)
                const bool needmask = (kh + 63 > mb);
                const int qrow = mb + l16;
#pragma unroll
                for (int c = 0; c < 4; c++) {
                    float e0 = exp2f(s4[c][0]);
                    float e1 = exp2f(s4[c][1]);
                    float e2 = exp2f(s4[c][2]);
                    float e3 = exp2f(s4[c][3]);
                    if (needmask) {
                        int k = kh + c * 16 + quad * 4;
                        if (k + 0 > qrow) e0 = 0.f;
                        if (k + 1 > qrow) e1 = 0.f;
                        if (k + 2 > qrow) e2 = 0.f;
                        if (k + 3 > qrow) e3 = 0.f;
                    }
                    *(uint32_t*)(pw + c * 16 + quad * 4) = permpack(e0, e1);
                    *(uint32_t*)(pw + c * 16 + quad * 4 + 2) = permpack(e2, e3);
                }
                bf16x8 pa[2];
#pragma unroll
                for (int pr = 0; pr < 2; pr++)
                    pa[pr] = *(const bf16x8*)(pw + pr * 32 + quad * 8);

#pragma unroll
                for (int nb = 0; nb < 4; nb++) {
                    oT[nb] = mfma16(vf[nb][0], pa[0], oT[nb]);
                    oT[nb] = mfma16(vf[nb][1], pa[1], oT[nb]);
                }
                ls = mfma16(one8.v, pa[0], ls);
                ls = mfma16(one8.v, pa[1], ls);
            }
            cur ^= 1;
        }

        float inv = 1.0f / ls[0];
        int srow = mb + l16;
#pragma unroll
        for (int nb = 0; nb < 4; nb++) {
            ushort4 o;
            o.x = f2bf(oT[nb][0] * inv);
            o.y = f2bf(oT[nb][1] * inv);
            o.z = f2bf(oT[nb][2] * inv);
            o.w = f2bf(oT[nb][3] * inv);
            *(ushort4*)(mg + ((size_t)b * SEQ + srow) * DIM + h * HD + nb * 16 + quad * 4) = o;
        }
    }
}

// ---------------- output projection: 64x128 tiles (512 blocks = 2/CU) ----------------
__global__ __launch_bounds__(256) void k_out(const ushort_t* __restrict__ a_in,
                                             const ushort_t* __restrict__ wt,
                                             float* __restrict__ out) {
    __shared__ __align__(16) ushort_t lA[64 * 64];  // 8 KB
    __shared__ __align__(16) ushort_t lB[128 * 64]; // 16 KB
    const int tid = threadIdx.x;
    const int wave = tid >> 6;
    const int lane = tid & 63;
    const int l16 = lane & 15;
    const int quad = lane >> 4;
    const int m0 = blockIdx.x * 64;
    const int n0 = blockIdx.y * 128;
    const int mw = (wave & 1) * 32, nw = (wave >> 1) * 64;

    const f32x4 zero4 = {0.f, 0.f, 0.f, 0.f};
    f32x4 acc[4][2];
#pragma unroll
    for (int i = 0; i < 4; i++)
#pragma unroll
        for (int j = 0; j < 2; j++) acc[i][j] = zero4;

    const int swz = l16 & 7;
    for (int k0 = 0; k0 < DIM; k0 += 64) {
        __syncthreads();
#pragma unroll
        for (int j = 0; j < 2; j++) {
            int base = wave * 128 + j * 64;
            int L = base + lane;
            int row = L >> 3, cd = L & 7;
            int cs = cd ^ (row & 7);
            glds16(a_in + (size_t)(m0 + row) * DIM + k0 + cs * 8, lA + base * 8);
        }
#pragma unroll
        for (int j = 0; j < 4; j++) {
            int base = wave * 256 + j * 64;
            int L = base + lane;
            int row = L >> 3, cd = L & 7;
            int cs = cd ^ (row & 7);
            glds16(wt + (size_t)(n0 + row) * DIM + k0 + cs * 8, lB + base * 8);
        }
        __syncthreads();
#pragma unroll
        for (int kk = 0; kk < 2; kk++) {
            bf16x8 a[2], b[4];
#pragma unroll
            for (int i = 0; i < 2; i++) {
                int rowa = mw + i * 16 + l16;
                int ch = (kk * 4 + quad) ^ swz;
                a[i] = *(const bf16x8*)(lA + rowa * 64 + ch * 8);
            }
#pragma unroll
            for (int i = 0; i < 4; i++) {
                int rowb = nw + i * 16 + l16;
                int ch = (kk * 4 + quad) ^ swz;
                b[i] = *(const bf16x8*)(lB + rowb * 64 + ch * 8);
            }
#pragma unroll
            for (int ni = 0; ni < 4; ni++)
#pragma unroll
                for (int mi = 0; mi < 2; mi++)
                    acc[ni][mi] = mfma16(b[ni], a[mi], acc[ni][mi]);
        }
    }

    // D[row=n][col=m]: lane holds 4 consecutive n at row m -> float4 store
#pragma unroll
    for (int ni = 0; ni < 4; ni++)
#pragma unroll
        for (int mi = 0; mi < 2; mi++) {
            int nbase = n0 + nw + ni * 16 + quad * 4;
            int m = m0 + mw + mi * 16 + l16;
            *(float4*)(out + (size_t)m * DIM + nbase) = *(float4*)&acc[ni][mi];
        }
}

extern "C" void kernel_launch(void* const* d_in, const int* in_sizes, int n_in,
                              void* d_out, int out_size, void* d_ws, size_t ws_size,
                              hipStream_t stream) {
    const float* x  = (const float*)d_in[0];
    const float* qw = (const float*)d_in[1];
    const float* kw = (const float*)d_in[2];
    const float* vw = (const float*)d_in[3];
    const float* ow = (const float*)d_in[4];
    float* out = (float*)d_out;

    ushort_t* xb = (ushort_t*)d_ws;                      // [4096][1024] bf16 x
    ushort_t* wt = xb + (size_t)MTOT * DIM;              // 4x [1024][1024] permuted weights^T
    ushort_t* qp = wt + (size_t)4 * DIM * DIM;           // [4096][1024] head-permuted Q (pre-scaled)
    ushort_t* kp = qp + (size_t)MTOT * DIM;              // K
    ushort_t* vp = kp + (size_t)MTOT * DIM;              // V row-major
    ushort_t* vt = vp + (size_t)MTOT * DIM;              // [32][64][2048] V^T per head
    ushort_t* mg = xb;                                   // reuse xb: dead after k_qkv

    k_prep<<<dim3(32, 32, 5), dim3(32, 8), 0, stream>>>(x, qw, kw, vw, ow, wt, xb);
    k_qkv<<<dim3(MTOT / 128, DIM / 128, 3), dim3(256), 0, stream>>>(xb, wt, qp, kp, vp);
    k_vt<<<dim3(SEQ / 32, HD / 32, BATCH * HEADS), dim3(32, 8), 0, stream>>>(vp, vt);
    k_attn<<<dim3(SEQ / 128, BATCH * HEADS), dim3(256), 0, stream>>>(qp, kp, vt, mg);
    k_out<<<dim3(MTOT / 64, DIM / 128), dim3(256), 0, stream>>>(mg, wt + (size_t)3 * DIM * DIM, out);
}